// Round 8
// baseline (463.425 us; speedup 1.0000x reference)
//
#include <hip/hip_runtime.h>
#include <hip/hip_bf16.h>

#define NNODES 90112
#define BGRAPH 4096
#define NPG 22
#define DBB 256
#define DNODE 128
#define DPROJ 256
#define DGIN 64
#define DGOUT 128

// ws layout (bf16 elems):
//   [0,        32768)  WTp   [256 cols][128 k]   (w_proj^T)
//   [32768,   622592)  WTg   [768 cols][768 k]   (cols: z|r|h gates; k: z|x_proj|prev_h)
//   [622592,  688128)  WThh  [256 cols][256 k]
// then f32 at byte offset 688128*2: bz[256], br[256], bh[256] (combined biases)
#define WTG_OFF   32768
#define WTHH_OFF  622592
#define WS_BF16_ELEMS 688128

typedef __attribute__((ext_vector_type(8))) short bf16x8;
typedef __attribute__((ext_vector_type(4))) short bf16x4;
typedef __attribute__((ext_vector_type(4))) float f32x4;

__device__ __forceinline__ short f2bf(float f) {
  __hip_bfloat16 h = __float2bfloat16(f);
  return *reinterpret_cast<short*>(&h);
}
__device__ __forceinline__ float bf2f(short s) {
  union { unsigned int u; float f; } c;
  c.u = ((unsigned int)(unsigned short)s) << 16;
  return c.f;
}
__device__ __forceinline__ float fsig(float xv) {
  return __fdividef(1.0f, 1.0f + __expf(-xv));
}
__device__ __forceinline__ float ftanh(float xv) {
  return 1.0f - __fdividef(2.0f, __expf(2.0f * xv) + 1.0f);
}

__global__ void pack_weights(const float* __restrict__ w_proj,
                             const float* __restrict__ W_xz, const float* __restrict__ W_hz,
                             const float* __restrict__ W_xr, const float* __restrict__ W_hr,
                             const float* __restrict__ W_xh, const float* __restrict__ W_hh,
                             const float* __restrict__ b_xz, const float* __restrict__ b_hz,
                             const float* __restrict__ b_xr, const float* __restrict__ b_hr,
                             const float* __restrict__ b_xh, const float* __restrict__ b_hh,
                             __hip_bfloat16* __restrict__ wsb, float* __restrict__ wsf) {
  int i = blockIdx.x * 256 + threadIdx.x;
  if (i < 32768) {
    int c = i >> 7, k = i & 127;                 // WTp[c][k] = w_proj[k][c]
    wsb[i] = __float2bfloat16(w_proj[k * DPROJ + c]);
  } else if (i < WTHH_OFF) {
    int j = i - WTG_OFF;
    int c = j / 768, k = j - c * 768;
    const float* Wx; const float* Wh; int cc;
    if (c < 256)      { Wx = W_xz; Wh = W_hz; cc = c; }
    else if (c < 512) { Wx = W_xr; Wh = W_hr; cc = c - 256; }
    else              { Wx = W_xh; Wh = nullptr; cc = c - 512; }
    float v;
    if (k < 512) v = Wx[k * 256 + cc];
    else         v = Wh ? Wh[(k - 512) * 256 + cc] : 0.0f;
    wsb[i] = __float2bfloat16(v);
  } else if (i < WS_BF16_ELEMS) {
    int j = i - WTHH_OFF;
    int c = j >> 8, k = j & 255;                 // WThh[c][k] = W_hh[k][c]
    wsb[i] = __float2bfloat16(W_hh[k * 256 + c]);
  }
  if (i < 256) {
    wsf[i]       = b_xz[i] + b_hz[i];
    wsf[256 + i] = b_xr[i] + b_hr[i];
    wsf[512 + i] = b_xh[i] + b_hh[i];
  }
}

// fused[b] = [ mean_{22 rows} z , relu(u @ w_glob + b_glob) ]
__global__ void fused_head(const float* __restrict__ z, const float* __restrict__ u,
                           const float* __restrict__ w_glob, const float* __restrict__ b_glob,
                           float* __restrict__ out) {
  int b = blockIdx.x;
  int t = threadIdx.x;  // 128 threads
  __shared__ float us[DGIN];
  if (t < DGIN) us[t] = u[b * DGIN + t];
  __syncthreads();
  const float* zb = z + (size_t)b * NPG * DBB;
  #pragma unroll
  for (int half = 0; half < 2; ++half) {
    int c = t + half * 128;
    float s = 0.f;
    #pragma unroll
    for (int r = 0; r < NPG; ++r) s += zb[r * DBB + c];
    out[(size_t)b * 384 + c] = s * (1.0f / NPG);
  }
  float acc = b_glob[t];
  #pragma unroll
  for (int k = 0; k < DGIN; ++k) acc += us[k] * w_glob[k * DGOUT + t];
  out[(size_t)b * 384 + 256 + t] = fmaxf(acc, 0.f);
}

#define MFMA16(a, b, c) __builtin_amdgcn_mfma_f32_16x16x32_bf16(a, b, c, 0, 0, 0)

// One source-tile K=256 sweep over a 32-row tile. a = weights (wave's 32 cols,
// 2 ct), b = act rows (2 rt). 12 (or 8) MFMA per kb step.
template<bool DO_H>
__device__ __forceinline__ void gate_pass32(
    const __hip_bfloat16* __restrict__ tile,   // [32][256] swizzled activations
    const __hip_bfloat16* __restrict__ WTG, int ksrc,
    int l15, int lg, int l7, int c0,
    f32x4 (&accz)[2][2], f32x4 (&accr)[2][2], f32x4 (&acch)[2][2]) {
  const __hip_bfloat16* p0 = WTG + (size_t)(c0 + l15) * 768 + ksrc * 256 + lg * 8;
  #pragma unroll
  for (int kb = 0; kb < 8; ++kb) {
    bf16x8 wz[2], wr[2], wh[2];
    #pragma unroll
    for (int ct = 0; ct < 2; ++ct) {
      const __hip_bfloat16* p = p0 + ct * (16 * 768) + kb * 32;
      wz[ct] = *(const bf16x8*)(p);
      wr[ct] = *(const bf16x8*)(p + 196608);   // +256*768
      if (DO_H) wh[ct] = *(const bf16x8*)(p + 393216);  // +512*768
    }
    const int gk = (kb * 4 + lg) ^ l7;
    bf16x8 act[2];
    #pragma unroll
    for (int rt = 0; rt < 2; ++rt)
      act[rt] = *(const bf16x8*)(tile + (rt * 16 + l15) * 256 + gk * 8);
    __builtin_amdgcn_s_setprio(1);
    #pragma unroll
    for (int ct = 0; ct < 2; ++ct)
      #pragma unroll
      for (int rt = 0; rt < 2; ++rt) {
        accz[ct][rt] = MFMA16(wz[ct], act[rt], accz[ct][rt]);
        accr[ct][rt] = MFMA16(wr[ct], act[rt], accr[ct][rt]);
        if (DO_H) acch[ct][rt] = MFMA16(wh[ct], act[rt], acch[ct][rt]);
      }
    __builtin_amdgcn_s_setprio(0);
  }
}

// Fused GRU body: 32 rows/block, 512 threads = 8 waves, each wave owns 32
// weight-cols x 32 rows (48 f32 acc/lane). 40 KB LDS + <=128 regs -> 2 blocks
// resident per CU: block-level phase overlap replaces intra-block pipelining.
__global__ __launch_bounds__(512, 4)
void grnn_main(const float* __restrict__ z, const float* __restrict__ x,
               const float* __restrict__ prev_h, const float* __restrict__ b_proj,
               const __hip_bfloat16* __restrict__ wsb, const float* __restrict__ wsf,
               float* __restrict__ h_out) {
  __shared__ __align__(16) __hip_bfloat16 Xs[32 * 128];
  __shared__ __align__(16) __hip_bfloat16 A0[32 * 256];  // z, then ph
  __shared__ __align__(16) __hip_bfloat16 A1[32 * 256];  // xp, then T

  const int r0   = blockIdx.x * 32;
  const int tid  = threadIdx.x;
  const int wid  = tid >> 6;          // 0..7
  const int lane = tid & 63;
  const int l15  = lane & 15;
  const int lg   = lane >> 4;         // 0..3
  const int l7   = l15 & 7;
  const int c0   = wid * 32;          // wave's 32-col slice
  const int cgrpb = (c0 >> 3) + (lg >> 1);  // + ct*2
  const int lgl  = (lg & 1) * 4;

  // ---- P0: stage x -> Xs (32x16 granules = 512) and z -> A0 ----
  {
    int row = tid >> 4, c8 = tid & 15;
    const float* p = x + (size_t)(r0 + row) * DNODE + c8 * 8;
    f32x4 f0 = __builtin_nontemporal_load((const f32x4*)p);
    f32x4 f1 = __builtin_nontemporal_load((const f32x4*)(p + 4));
    bf16x8 o;
    o[0]=f2bf(f0[0]); o[1]=f2bf(f0[1]); o[2]=f2bf(f0[2]); o[3]=f2bf(f0[3]);
    o[4]=f2bf(f1[0]); o[5]=f2bf(f1[1]); o[6]=f2bf(f1[2]); o[7]=f2bf(f1[3]);
    *(bf16x8*)&Xs[row * 128 + (c8 ^ (row & 7)) * 8] = o;
  }
  #pragma unroll
  for (int i = 0; i < 2; ++i) {
    int g = tid + i * 512;
    int row = g >> 5, c8 = g & 31;
    const float* p = z + (size_t)(r0 + row) * DBB + c8 * 8;
    f32x4 f0 = __builtin_nontemporal_load((const f32x4*)p);
    f32x4 f1 = __builtin_nontemporal_load((const f32x4*)(p + 4));
    bf16x8 o;
    o[0]=f2bf(f0[0]); o[1]=f2bf(f0[1]); o[2]=f2bf(f0[2]); o[3]=f2bf(f0[3]);
    o[4]=f2bf(f1[0]); o[5]=f2bf(f1[1]); o[6]=f2bf(f1[2]); o[7]=f2bf(f1[3]);
    *(bf16x8*)&A0[row * 256 + (c8 ^ (row & 7)) * 8] = o;
  }
  __syncthreads();

  // ---- P1: issue ph loads; x_proj GEMM; write xp -> A1 ----
  f32x4 slp[4];
  #pragma unroll
  for (int i = 0; i < 2; ++i) {
    int g = tid + i * 512;
    int row = g >> 5, c8 = g & 31;
    const float* pp = prev_h + (size_t)(r0 + row) * DBB + c8 * 8;
    slp[2 * i]     = __builtin_nontemporal_load((const f32x4*)pp);
    slp[2 * i + 1] = __builtin_nontemporal_load((const f32x4*)(pp + 4));
  }
  f32x4 accp[2][2] = {};
  {
    const __hip_bfloat16* wp0 = wsb + (size_t)(c0 + l15) * DNODE + lg * 8;
    #pragma unroll
    for (int kb = 0; kb < 4; ++kb) {
      bf16x8 wp[2];
      #pragma unroll
      for (int ct = 0; ct < 2; ++ct)
        wp[ct] = *(const bf16x8*)(wp0 + ct * (16 * DNODE) + kb * 32);
      const int gk = (kb * 4 + lg) ^ l7;
      bf16x8 act[2];
      #pragma unroll
      for (int rt = 0; rt < 2; ++rt)
        act[rt] = *(const bf16x8*)&Xs[(rt * 16 + l15) * 128 + gk * 8];
      __builtin_amdgcn_s_setprio(1);
      #pragma unroll
      for (int ct = 0; ct < 2; ++ct)
        #pragma unroll
        for (int rt = 0; rt < 2; ++rt)
          accp[ct][rt] = MFMA16(wp[ct], act[rt], accp[ct][rt]);
      __builtin_amdgcn_s_setprio(0);
    }
  }
  #pragma unroll
  for (int ct = 0; ct < 2; ++ct) {
    float4 bp4 = *(const float4*)&b_proj[c0 + ct * 16 + lg * 4];
    int cgrp = cgrpb + ct * 2;
    #pragma unroll
    for (int rt = 0; rt < 2; ++rt) {
      int r = rt * 16 + l15;
      bf16x4 o;
      o[0] = f2bf(fmaxf(accp[ct][rt][0] + bp4.x, 0.f));
      o[1] = f2bf(fmaxf(accp[ct][rt][1] + bp4.y, 0.f));
      o[2] = f2bf(fmaxf(accp[ct][rt][2] + bp4.z, 0.f));
      o[3] = f2bf(fmaxf(accp[ct][rt][3] + bp4.w, 0.f));
      *(bf16x4*)&A1[r * 256 + ((cgrp ^ (r & 7)) * 8) + lgl] = o;
    }
  }
  __syncthreads();

  // ---- P2: sweep z (A0): all 3 gates ----
  const __hip_bfloat16* WTG = wsb + WTG_OFF;
  f32x4 accz[2][2] = {}, accr[2][2] = {}, acch[2][2] = {};
  gate_pass32<true>(A0, WTG, 0, l15, lg, l7, c0, accz, accr, acch);
  __syncthreads();   // A0 free

  // ---- P3: write ph -> A0; sweep xp (A1) ----
  #pragma unroll
  for (int i = 0; i < 2; ++i) {
    int g = tid + i * 512;
    int row = g >> 5, c8 = g & 31;
    f32x4 f0 = slp[2 * i], f1 = slp[2 * i + 1];
    bf16x8 o;
    o[0]=f2bf(f0[0]); o[1]=f2bf(f0[1]); o[2]=f2bf(f0[2]); o[3]=f2bf(f0[3]);
    o[4]=f2bf(f1[0]); o[5]=f2bf(f1[1]); o[6]=f2bf(f1[2]); o[7]=f2bf(f1[3]);
    *(bf16x8*)&A0[row * 256 + (c8 ^ (row & 7)) * 8] = o;
  }
  gate_pass32<true>(A1, WTG, 1, l15, lg, l7, c0, accz, accr, acch);
  __syncthreads();   // ph staged, A1 free

  // ---- P4: sweep ph (A0, z/r gates); T = ph*sigmoid(Ar) -> A1 ----
  gate_pass32<false>(A0, WTG, 2, l15, lg, l7, c0, accz, accr, acch);
  #pragma unroll
  for (int ct = 0; ct < 2; ++ct) {
    float4 br4 = *(const float4*)&wsf[256 + c0 + ct * 16 + lg * 4];
    int cgrp = cgrpb + ct * 2;
    #pragma unroll
    for (int rt = 0; rt < 2; ++rt) {
      int r = rt * 16 + l15;
      int off = r * 256 + ((cgrp ^ (r & 7)) * 8) + lgl;
      bf16x4 p4 = *(const bf16x4*)&A0[off];
      bf16x4 o;
      o[0] = f2bf(bf2f(p4[0]) * fsig(accr[ct][rt][0] + br4.x));
      o[1] = f2bf(bf2f(p4[1]) * fsig(accr[ct][rt][1] + br4.y));
      o[2] = f2bf(bf2f(p4[2]) * fsig(accr[ct][rt][2] + br4.z));
      o[3] = f2bf(bf2f(p4[3]) * fsig(accr[ct][rt][3] + br4.w));
      *(bf16x4*)&A1[off] = o;
    }
  }
  __syncthreads();   // T complete

  // ---- P5: acch += T @ W_hh (A1); epilogue ----
  {
    const __hip_bfloat16* h0 = wsb + WTHH_OFF + (size_t)(c0 + l15) * 256 + lg * 8;
    #pragma unroll
    for (int kb = 0; kb < 8; ++kb) {
      bf16x8 wv[2];
      #pragma unroll
      for (int ct = 0; ct < 2; ++ct)
        wv[ct] = *(const bf16x8*)(h0 + ct * (16 * 256) + kb * 32);
      const int gk = (kb * 4 + lg) ^ l7;
      bf16x8 act[2];
      #pragma unroll
      for (int rt = 0; rt < 2; ++rt)
        act[rt] = *(const bf16x8*)&A1[(rt * 16 + l15) * 256 + gk * 8];
      __builtin_amdgcn_s_setprio(1);
      #pragma unroll
      for (int ct = 0; ct < 2; ++ct)
        #pragma unroll
        for (int rt = 0; rt < 2; ++rt)
          acch[ct][rt] = MFMA16(wv[ct], act[rt], acch[ct][rt]);
      __builtin_amdgcn_s_setprio(0);
    }
  }
  #pragma unroll
  for (int ct = 0; ct < 2; ++ct) {
    float4 bz4 = *(const float4*)&wsf[c0 + ct * 16 + lg * 4];
    float4 bh4 = *(const float4*)&wsf[512 + c0 + ct * 16 + lg * 4];
    int cgrp = cgrpb + ct * 2;
    #pragma unroll
    for (int rt = 0; rt < 2; ++rt) {
      int r = rt * 16 + l15;
      bf16x4 p4 = *(const bf16x4*)&A0[r * 256 + ((cgrp ^ (r & 7)) * 8) + lgl];
      f32x4 hv;
      float zg = fsig(accz[ct][rt][0] + bz4.x);
      hv[0] = zg * bf2f(p4[0]) + (1.f - zg) * ftanh(acch[ct][rt][0] + bh4.x);
      zg = fsig(accz[ct][rt][1] + bz4.y);
      hv[1] = zg * bf2f(p4[1]) + (1.f - zg) * ftanh(acch[ct][rt][1] + bh4.y);
      zg = fsig(accz[ct][rt][2] + bz4.z);
      hv[2] = zg * bf2f(p4[2]) + (1.f - zg) * ftanh(acch[ct][rt][2] + bh4.z);
      zg = fsig(accz[ct][rt][3] + bz4.w);
      hv[3] = zg * bf2f(p4[3]) + (1.f - zg) * ftanh(acch[ct][rt][3] + bh4.w);
      __builtin_nontemporal_store(hv, (f32x4*)&h_out[(size_t)(r0 + r) * DBB + c0 + ct * 16 + lg * 4]);
    }
  }
}

extern "C" void kernel_launch(void* const* d_in, const int* in_sizes, int n_in,
                              void* d_out, int out_size, void* d_ws, size_t ws_size,
                              hipStream_t stream) {
  const float* z      = (const float*)d_in[0];
  const float* u      = (const float*)d_in[1];
  const float* x      = (const float*)d_in[2];
  const float* prev_h = (const float*)d_in[6];
  const float* w_proj = (const float*)d_in[7];
  const float* b_proj = (const float*)d_in[8];
  const float* w_glob = (const float*)d_in[9];
  const float* b_glob = (const float*)d_in[10];
  const float* W_xz   = (const float*)d_in[11];
  const float* b_xz   = (const float*)d_in[12];
  const float* W_hz   = (const float*)d_in[13];
  const float* b_hz   = (const float*)d_in[14];
  const float* W_xr   = (const float*)d_in[15];
  const float* b_xr   = (const float*)d_in[16];
  const float* W_hr   = (const float*)d_in[17];
  const float* b_hr   = (const float*)d_in[18];
  const float* W_xh   = (const float*)d_in[19];
  const float* b_xh   = (const float*)d_in[20];
  const float* W_hh   = (const float*)d_in[21];
  const float* b_hh   = (const float*)d_in[22];

  __hip_bfloat16* wsb = (__hip_bfloat16*)d_ws;
  float* wsf = (float*)((char*)d_ws + (size_t)WS_BF16_ELEMS * 2);

  float* fused = (float*)d_out;
  float* h_out = fused + (size_t)BGRAPH * 384;

  pack_weights<<<dim3(WS_BF16_ELEMS / 256), dim3(256), 0, stream>>>(
      w_proj, W_xz, W_hz, W_xr, W_hr, W_xh, W_hh,
      b_xz, b_hz, b_xr, b_hr, b_xh, b_hh, wsb, wsf);

  // head first: warms L3 with z before the main pass
  fused_head<<<dim3(BGRAPH), dim3(128), 0, stream>>>(z, u, w_glob, b_glob, fused);

  grnn_main<<<dim3(NNODES / 32), dim3(512), 0, stream>>>(
      z, x, prev_h, b_proj, wsb, wsf, h_out);
}

// Round 9
// 322.925 us; speedup vs baseline: 1.4351x; 1.4351x over previous
//
#include <hip/hip_runtime.h>
#include <hip/hip_bf16.h>

#define NNODES 90112
#define BGRAPH 4096
#define NPG 22
#define DBB 256
#define DNODE 128
#define DPROJ 256
#define DGIN 64
#define DGOUT 128

// ws layout (bf16 elems):
//   [0,        32768)  WTp   [256 cols][128 k]   (w_proj^T)
//   [32768,   622592)  WTg   [768 cols][768 k]   (cols: z|r|h gates; k: z|x_proj|prev_h;
//                                                 h-gate k>=512 is ZERO-filled — used as no-op MFMA fodder)
//   [622592,  688128)  WThh  [256 cols][256 k]
// then f32 at byte offset 688128*2: bz[256], br[256], bh[256] (combined biases)
#define WTG_OFF   32768
#define WTHH_OFF  622592
#define WS_BF16_ELEMS 688128

typedef __attribute__((ext_vector_type(8))) short bf16x8;
typedef __attribute__((ext_vector_type(4))) short bf16x4;
typedef __attribute__((ext_vector_type(4))) float f32x4;

__device__ __forceinline__ short f2bf(float f) {
  __hip_bfloat16 h = __float2bfloat16(f);
  return *reinterpret_cast<short*>(&h);
}
__device__ __forceinline__ float bf2f(short s) {
  union { unsigned int u; float f; } c;
  c.u = ((unsigned int)(unsigned short)s) << 16;
  return c.f;
}
__device__ __forceinline__ float fsig(float xv) {
  return __fdividef(1.0f, 1.0f + __expf(-xv));
}
__device__ __forceinline__ float ftanh(float xv) {
  return 1.0f - __fdividef(2.0f, __expf(2.0f * xv) + 1.0f);
}

// asm 16B global load: compiler does NOT track vmcnt for this — we count manually.
#define GL(dst, p) asm volatile("global_load_dwordx4 %0, %1, off" : "=v"(dst) : "v"(p) : "memory")
// counted wait + scheduler fence (rule #18: sched_barrier right after the waitcnt)
#define VMWAIT(N) do { asm volatile("s_waitcnt vmcnt(" #N ")" ::: "memory"); \
                       __builtin_amdgcn_sched_barrier(0); } while (0)

__global__ void pack_weights(const float* __restrict__ w_proj,
                             const float* __restrict__ W_xz, const float* __restrict__ W_hz,
                             const float* __restrict__ W_xr, const float* __restrict__ W_hr,
                             const float* __restrict__ W_xh, const float* __restrict__ W_hh,
                             const float* __restrict__ b_xz, const float* __restrict__ b_hz,
                             const float* __restrict__ b_xr, const float* __restrict__ b_hr,
                             const float* __restrict__ b_xh, const float* __restrict__ b_hh,
                             __hip_bfloat16* __restrict__ wsb, float* __restrict__ wsf) {
  int i = blockIdx.x * 256 + threadIdx.x;
  if (i < 32768) {
    int c = i >> 7, k = i & 127;                 // WTp[c][k] = w_proj[k][c]
    wsb[i] = __float2bfloat16(w_proj[k * DPROJ + c]);
  } else if (i < WTHH_OFF) {
    int j = i - WTG_OFF;
    int c = j / 768, k = j - c * 768;
    const float* Wx; const float* Wh; int cc;
    if (c < 256)      { Wx = W_xz; Wh = W_hz; cc = c; }
    else if (c < 512) { Wx = W_xr; Wh = W_hr; cc = c - 256; }
    else              { Wx = W_xh; Wh = nullptr; cc = c - 512; }
    float v;
    if (k < 512) v = Wx[k * 256 + cc];
    else         v = Wh ? Wh[(k - 512) * 256 + cc] : 0.0f;
    wsb[i] = __float2bfloat16(v);
  } else if (i < WS_BF16_ELEMS) {
    int j = i - WTHH_OFF;
    int c = j >> 8, k = j & 255;                 // WThh[c][k] = W_hh[k][c]
    wsb[i] = __float2bfloat16(W_hh[k * 256 + c]);
  }
  if (i < 256) {
    wsf[i]       = b_xz[i] + b_hz[i];
    wsf[256 + i] = b_xr[i] + b_hr[i];
    wsf[512 + i] = b_xh[i] + b_hh[i];
  }
}

// fused[b] = [ mean_{22 rows} z , relu(u @ w_glob + b_glob) ]
__global__ void fused_head(const float* __restrict__ z, const float* __restrict__ u,
                           const float* __restrict__ w_glob, const float* __restrict__ b_glob,
                           float* __restrict__ out) {
  int b = blockIdx.x;
  int t = threadIdx.x;  // 128 threads
  __shared__ float us[DGIN];
  if (t < DGIN) us[t] = u[b * DGIN + t];
  __syncthreads();
  const float* zb = z + (size_t)b * NPG * DBB;
  #pragma unroll
  for (int half = 0; half < 2; ++half) {
    int c = t + half * 128;
    float s = 0.f;
    #pragma unroll
    for (int r = 0; r < NPG; ++r) s += zb[r * DBB + c];
    out[(size_t)b * 384 + c] = s * (1.0f / NPG);
  }
  float acc = b_glob[t];
  #pragma unroll
  for (int k = 0; k < DGIN; ++k) acc += us[k] * w_glob[k * DGOUT + t];
  out[(size_t)b * 384 + 256 + t] = fmaxf(acc, 0.f);
}

#define MFMA16(a, b, c) __builtin_amdgcn_mfma_f32_16x16x32_bf16(a, b, c, 0, 0, 0)

// Fused GRU body: 64 rows/block, 1024 threads = 16 waves, each wave owns 16
// weight-cols x 64 rows. Weight loads are inline-asm with depth-2 counted-vmcnt
// pipelining (T4): steady-state s_waitcnt vmcnt(3), never 0 mid-loop.
__global__ __launch_bounds__(1024)
void grnn_main(const float* __restrict__ z, const float* __restrict__ x,
               const float* __restrict__ prev_h, const float* __restrict__ b_proj,
               const __hip_bfloat16* __restrict__ wsb, const float* __restrict__ wsf,
               float* __restrict__ h_out) {
  __shared__ __align__(16) __hip_bfloat16 Xs[64 * 128];
  __shared__ __align__(16) __hip_bfloat16 Zs[64 * 256];
  __shared__ __align__(16) __hip_bfloat16 XPs[64 * 256];
  __shared__ __align__(16) __hip_bfloat16 PHs[64 * 256];
  __shared__ __align__(16) __hip_bfloat16 Ts[64 * 256];   // T = ph*sigmoid(Ar)

  const int r0   = blockIdx.x * 64;
  const int tid  = threadIdx.x;
  const int wid  = tid >> 6;          // 0..15
  const int lane = tid & 63;
  const int l15  = lane & 15;
  const int lg   = lane >> 4;         // 0..3
  const int l7   = l15 & 7;
  const int c0   = wid * 16;          // wave's 16-col slice
  const int cgrp = (c0 >> 3) + (lg >> 1);   // granule of lane's 4-col quad
  const int lgl  = (lg & 1) * 4;            // elem offset within granule

  // ---- P0: stage x -> Xs ([64][128], 16B-granule XOR swizzle) ----
  {
    int row = tid >> 4, c8 = tid & 15;
    const float* p = x + (size_t)(r0 + row) * DNODE + c8 * 8;
    f32x4 f0 = *(const f32x4*)p;
    f32x4 f1 = *(const f32x4*)(p + 4);
    bf16x8 o;
    o[0]=f2bf(f0[0]); o[1]=f2bf(f0[1]); o[2]=f2bf(f0[2]); o[3]=f2bf(f0[3]);
    o[4]=f2bf(f1[0]); o[5]=f2bf(f1[1]); o[6]=f2bf(f1[2]); o[7]=f2bf(f1[3]);
    *(bf16x8*)&Xs[row * 128 + (c8 ^ (row & 7)) * 8] = o;
  }
  __syncthreads();

  // ---- P1: issue z+ph loads, x_proj GEMM under them, then LDS writes ----
  f32x4 slz[4], slp[4];
  #pragma unroll
  for (int i = 0; i < 2; ++i) {
    int g = tid + i * 1024;
    int row = g >> 5, c8 = g & 31;
    const float* pz = z + (size_t)(r0 + row) * DBB + c8 * 8;
    const float* pp = prev_h + (size_t)(r0 + row) * DBB + c8 * 8;
    slz[2 * i]     = *(const f32x4*)pz;
    slz[2 * i + 1] = *(const f32x4*)(pz + 4);
    slp[2 * i]     = *(const f32x4*)pp;
    slp[2 * i + 1] = *(const f32x4*)(pp + 4);
  }
  f32x4 accp[4] = {};
  {
    const __hip_bfloat16* wp0 = wsb + (size_t)(c0 + l15) * DNODE + lg * 8;
    #pragma unroll
    for (int kb = 0; kb < 4; ++kb) {
      bf16x8 wp = *(const bf16x8*)(wp0 + kb * 32);
      const int gk = (kb * 4 + lg) ^ l7;
      bf16x8 act[4];
      #pragma unroll
      for (int rt = 0; rt < 4; ++rt)
        act[rt] = *(const bf16x8*)&Xs[(rt * 16 + l15) * 128 + gk * 8];
      __builtin_amdgcn_s_setprio(1);
      #pragma unroll
      for (int rt = 0; rt < 4; ++rt)
        accp[rt] = MFMA16(wp, act[rt], accp[rt]);
      __builtin_amdgcn_s_setprio(0);
    }
  }
  #pragma unroll
  for (int i = 0; i < 2; ++i) {
    int g = tid + i * 1024;
    int row = g >> 5, c8 = g & 31;
    int off = row * 256 + (c8 ^ (row & 7)) * 8;
    f32x4 f0 = slz[2 * i], f1 = slz[2 * i + 1];
    bf16x8 o;
    o[0]=f2bf(f0[0]); o[1]=f2bf(f0[1]); o[2]=f2bf(f0[2]); o[3]=f2bf(f0[3]);
    o[4]=f2bf(f1[0]); o[5]=f2bf(f1[1]); o[6]=f2bf(f1[2]); o[7]=f2bf(f1[3]);
    *(bf16x8*)&Zs[off] = o;
    f0 = slp[2 * i]; f1 = slp[2 * i + 1];
    o[0]=f2bf(f0[0]); o[1]=f2bf(f0[1]); o[2]=f2bf(f0[2]); o[3]=f2bf(f0[3]);
    o[4]=f2bf(f1[0]); o[5]=f2bf(f1[1]); o[6]=f2bf(f1[2]); o[7]=f2bf(f1[3]);
    *(bf16x8*)&PHs[off] = o;
  }
  {
    float4 bp4 = *(const float4*)&b_proj[c0 + lg * 4];
    #pragma unroll
    for (int rt = 0; rt < 4; ++rt) {
      int r = rt * 16 + l15;
      bf16x4 o;
      o[0] = f2bf(fmaxf(accp[rt][0] + bp4.x, 0.f));
      o[1] = f2bf(fmaxf(accp[rt][1] + bp4.y, 0.f));
      o[2] = f2bf(fmaxf(accp[rt][2] + bp4.z, 0.f));
      o[3] = f2bf(fmaxf(accp[rt][3] + bp4.w, 0.f));
      *(bf16x4*)&XPs[r * 256 + ((cgrp ^ (r & 7)) * 8) + lgl] = o;
    }
  }
  __syncthreads();

  // ---- P2: unified gate sweep, 24 uniform steps (3 sources x 8 kb) ----
  // Per step: 3 asm weight loads (z,r,h gates) + 4 act ds_reads + 12 MFMA.
  // Steps 16..23 read the zero-filled h region (exact no-op accumulate).
  f32x4 accz[4] = {}, accr[4] = {}, acch[4] = {};
  {
    const __hip_bfloat16* wb_z = wsb + WTG_OFF + (size_t)(c0 + l15) * 768 + lg * 8;
    const __hip_bfloat16* wb_r = wb_z + 196608;   // +256*768
    const __hip_bfloat16* wb_h = wb_z + 393216;   // +512*768
    bf16x8 wz3[3], wr3[3], wh3[3];
    // prologue: steps 0,1 in flight (issue order z,r,h per step)
    GL(wz3[0], wb_z);      GL(wr3[0], wb_r);      GL(wh3[0], wb_h);
    GL(wz3[1], wb_z + 32); GL(wr3[1], wb_r + 32); GL(wh3[1], wb_h + 32);

    const __hip_bfloat16* const tp[3] = { Zs, XPs, PHs };
    #pragma unroll
    for (int s = 0; s < 24; ++s) {
      const int ks = s >> 3, kb = s & 7;
      const int gk = (kb * 4 + lg) ^ l7;
      const __hip_bfloat16* t_ = tp[ks];
      bf16x8 act[4];
      #pragma unroll
      for (int rt = 0; rt < 4; ++rt)
        act[rt] = *(const bf16x8*)(t_ + (rt * 16 + l15) * 256 + gk * 8);
      if (s < 23) VMWAIT(3); else VMWAIT(0);
      const int cs = s % 3;
      __builtin_amdgcn_s_setprio(1);
      #pragma unroll
      for (int rt = 0; rt < 4; ++rt) {
        accz[rt] = MFMA16(wz3[cs], act[rt], accz[rt]);
        accr[rt] = MFMA16(wr3[cs], act[rt], accr[rt]);
        acch[rt] = MFMA16(wh3[cs], act[rt], acch[rt]);
      }
      __builtin_amdgcn_s_setprio(0);
      if (s < 22) {
        const int s2 = s + 2;
        const int e2 = (s2 >> 3) * 256 + (s2 & 7) * 32;
        const int n2 = s2 % 3;
        GL(wz3[n2], wb_z + e2); GL(wr3[n2], wb_r + e2); GL(wh3[n2], wb_h + e2);
      }
    }
  }

  // T = ph * sigmoid(A_r + br) -> Ts
  {
    float4 br4 = *(const float4*)&wsf[256 + c0 + lg * 4];
    #pragma unroll
    for (int rt = 0; rt < 4; ++rt) {
      int r = rt * 16 + l15;
      int off = r * 256 + ((cgrp ^ (r & 7)) * 8) + lgl;
      bf16x4 p4 = *(const bf16x4*)&PHs[off];
      bf16x4 o;
      o[0] = f2bf(bf2f(p4[0]) * fsig(accr[rt][0] + br4.x));
      o[1] = f2bf(bf2f(p4[1]) * fsig(accr[rt][1] + br4.y));
      o[2] = f2bf(bf2f(p4[2]) * fsig(accr[rt][2] + br4.z));
      o[3] = f2bf(bf2f(p4[3]) * fsig(accr[rt][3] + br4.w));
      *(bf16x4*)&Ts[off] = o;
    }
  }
  __syncthreads();

  // ---- P3: acch += T @ W_hh (8 steps, same asm pipeline, 1 load/step) ----
  {
    const __hip_bfloat16* hb = wsb + WTHH_OFF + (size_t)(c0 + l15) * 256 + lg * 8;
    bf16x8 hw3[3];
    GL(hw3[0], hb); GL(hw3[1], hb + 32);
    #pragma unroll
    for (int s = 0; s < 8; ++s) {
      const int gk = (s * 4 + lg) ^ l7;
      bf16x8 act[4];
      #pragma unroll
      for (int rt = 0; rt < 4; ++rt)
        act[rt] = *(const bf16x8*)&Ts[(rt * 16 + l15) * 256 + gk * 8];
      if (s < 7) VMWAIT(1); else VMWAIT(0);
      const int cs = s % 3;
      __builtin_amdgcn_s_setprio(1);
      #pragma unroll
      for (int rt = 0; rt < 4; ++rt)
        acch[rt] = MFMA16(hw3[cs], act[rt], acch[rt]);
      __builtin_amdgcn_s_setprio(0);
      if (s < 6) GL(hw3[(s + 2) % 3], hb + (s + 2) * 32);
    }
  }

  // ---- epilogue: h = Z*ph + (1-Z)*tanh(A_h); coalesced f32x4 stores ----
  {
    float4 bz4 = *(const float4*)&wsf[c0 + lg * 4];
    float4 bh4 = *(const float4*)&wsf[512 + c0 + lg * 4];
    #pragma unroll
    for (int rt = 0; rt < 4; ++rt) {
      int r = rt * 16 + l15;
      bf16x4 p4 = *(const bf16x4*)&PHs[r * 256 + ((cgrp ^ (r & 7)) * 8) + lgl];
      f32x4 hv;
      float zg = fsig(accz[rt][0] + bz4.x);
      hv[0] = zg * bf2f(p4[0]) + (1.f - zg) * ftanh(acch[rt][0] + bh4.x);
      zg = fsig(accz[rt][1] + bz4.y);
      hv[1] = zg * bf2f(p4[1]) + (1.f - zg) * ftanh(acch[rt][1] + bh4.y);
      zg = fsig(accz[rt][2] + bz4.z);
      hv[2] = zg * bf2f(p4[2]) + (1.f - zg) * ftanh(acch[rt][2] + bh4.z);
      zg = fsig(accz[rt][3] + bz4.w);
      hv[3] = zg * bf2f(p4[3]) + (1.f - zg) * ftanh(acch[rt][3] + bh4.w);
      *(f32x4*)&h_out[(size_t)(r0 + r) * DBB + c0 + lg * 4] = hv;
    }
  }
}

extern "C" void kernel_launch(void* const* d_in, const int* in_sizes, int n_in,
                              void* d_out, int out_size, void* d_ws, size_t ws_size,
                              hipStream_t stream) {
  const float* z      = (const float*)d_in[0];
  const float* u      = (const float*)d_in[1];
  const float* x      = (const float*)d_in[2];
  const float* prev_h = (const float*)d_in[6];
  const float* w_proj = (const float*)d_in[7];
  const float* b_proj = (const float*)d_in[8];
  const float* w_glob = (const float*)d_in[9];
  const float* b_glob = (const float*)d_in[10];
  const float* W_xz   = (const float*)d_in[11];
  const float* b_xz   = (const float*)d_in[12];
  const float* W_hz   = (const float*)d_in[13];
  const float* b_hz   = (const float*)d_in[14];
  const float* W_xr   = (const float*)d_in[15];
  const float* b_xr   = (const float*)d_in[16];
  const float* W_hr   = (const float*)d_in[17];
  const float* b_hr   = (const float*)d_in[18];
  const float* W_xh   = (const float*)d_in[19];
  const float* b_xh   = (const float*)d_in[20];
  const float* W_hh   = (const float*)d_in[21];
  const float* b_hh   = (const float*)d_in[22];

  __hip_bfloat16* wsb = (__hip_bfloat16*)d_ws;
  float* wsf = (float*)((char*)d_ws + (size_t)WS_BF16_ELEMS * 2);

  float* fused = (float*)d_out;
  float* h_out = fused + (size_t)BGRAPH * 384;

  pack_weights<<<dim3(WS_BF16_ELEMS / 256), dim3(256), 0, stream>>>(
      w_proj, W_xz, W_hz, W_xr, W_hr, W_xh, W_hh,
      b_xz, b_hz, b_xr, b_hr, b_xh, b_hh, wsb, wsf);

  // head first: warms L3 with z before the main pass
  fused_head<<<dim3(BGRAPH), dim3(128), 0, stream>>>(z, u, w_glob, b_glob, fused);

  grnn_main<<<dim3(NNODES / 64), dim3(1024), 0, stream>>>(
      z, x, prev_h, b_proj, wsb, wsf, h_out);
}

// Round 10
// 234.754 us; speedup vs baseline: 1.9741x; 1.3756x over previous
//
#include <hip/hip_runtime.h>
#include <hip/hip_bf16.h>

#define NNODES 90112
#define BGRAPH 4096
#define NPG 22
#define DBB 256
#define DNODE 128
#define DPROJ 256
#define DGIN 64
#define DGOUT 128

// ws bf16 layout:
//   [0, 32768)           WTp  [256 cols][128 k]  (w_proj^T, read per-wave)
//   [32768, 622592)      Wpk  gate weights, DMA-packed:
//                        elem ((kc*48 + ct)*64 + lane)*8 + e ; kc 0..23 (K-chunk of 32),
//                        ct 0..47 (ct>>4 = gate z/r/h, col = (ct&15)*16 + (lane&15)),
//                        k = kc*32 + (lane>>4)*8 + e.  h-gate k>=512 not stored (skipped).
//   [622592, 688128)     Whhpk same scheme: kc 0..7, ct 0..15, col = ct*16+l15.
// f32 tail: bz[256], br[256], bh[256]
#define WTG_OFF   32768
#define WTHH_OFF  622592
#define WS_BF16_ELEMS 688128

typedef __attribute__((ext_vector_type(8))) short bf16x8;
typedef __attribute__((ext_vector_type(4))) short bf16x4;
typedef __attribute__((ext_vector_type(4))) float f32x4;

__device__ __forceinline__ short f2bf(float f) {
  __hip_bfloat16 h = __float2bfloat16(f);
  return *reinterpret_cast<short*>(&h);
}
__device__ __forceinline__ float bf2f(short s) {
  union { unsigned int u; float f; } c;
  c.u = ((unsigned int)(unsigned short)s) << 16;
  return c.f;
}
__device__ __forceinline__ float fsig(float xv) {
  return __fdividef(1.0f, 1.0f + __expf(-xv));
}
__device__ __forceinline__ float ftanh(float xv) {
  return 1.0f - __fdividef(2.0f, __expf(2.0f * xv) + 1.0f);
}

// async global->LDS DMA, 16B/lane: LDS dest = uniform base + lane*16 (HW),
// global src = per-lane pointer. Tracked by vmcnt (compiler-visible builtin).
#define DMA16(gsrc, ldst)                                                        \
  __builtin_amdgcn_global_load_lds(                                              \
      (const __attribute__((address_space(1))) void*)(gsrc),                     \
      (__attribute__((address_space(3))) void*)(ldst), 16, 0, 0)

#define VMWAIT(N) do { asm volatile("s_waitcnt vmcnt(" #N ")" ::: "memory");     \
                       __builtin_amdgcn_sched_barrier(0); } while (0)
#define LBAR() do { asm volatile("s_waitcnt lgkmcnt(0)" ::: "memory");           \
                    __builtin_amdgcn_s_barrier(); } while (0)

__global__ void pack_weights(const float* __restrict__ w_proj,
                             const float* __restrict__ W_xz, const float* __restrict__ W_hz,
                             const float* __restrict__ W_xr, const float* __restrict__ W_hr,
                             const float* __restrict__ W_xh, const float* __restrict__ W_hh,
                             const float* __restrict__ b_xz, const float* __restrict__ b_hz,
                             const float* __restrict__ b_xr, const float* __restrict__ b_hr,
                             const float* __restrict__ b_xh, const float* __restrict__ b_hh,
                             __hip_bfloat16* __restrict__ wsb, float* __restrict__ wsf) {
  int i = blockIdx.x * 256 + threadIdx.x;
  if (i < 32768) {
    int c = i >> 7, k = i & 127;                 // WTp[c][k] = w_proj[k][c]
    wsb[i] = __float2bfloat16(w_proj[k * DPROJ + c]);
  } else if (i < WTHH_OFF) {
    int j = i - WTG_OFF;                         // gate DMA pack
    int kc  = j / 24576;                         // 48*512
    int rem = j - kc * 24576;
    int ct  = rem >> 9;
    int q   = rem & 511;
    int l   = q >> 3, e = q & 7;
    int l15 = l & 15, kg = l >> 4;
    int k   = kc * 32 + kg * 8 + e;              // 0..767
    int g   = ct >> 4;
    int c   = (ct & 15) * 16 + l15;
    float v;
    if (g == 0)      v = (k < 512) ? W_xz[k * 256 + c] : W_hz[(k - 512) * 256 + c];
    else if (g == 1) v = (k < 512) ? W_xr[k * 256 + c] : W_hr[(k - 512) * 256 + c];
    else             v = (k < 512) ? W_xh[k * 256 + c] : 0.0f;
    wsb[i] = __float2bfloat16(v);
  } else if (i < WS_BF16_ELEMS) {
    int j = i - WTHH_OFF;                        // Whh DMA pack
    int kc  = j >> 13;                           // /8192
    int rem = j & 8191;
    int ct  = rem >> 9;
    int q   = rem & 511;
    int l   = q >> 3, e = q & 7;
    int l15 = l & 15, kg = l >> 4;
    int k   = kc * 32 + kg * 8 + e;
    int c   = ct * 16 + l15;
    wsb[i] = __float2bfloat16(W_hh[k * 256 + c]);
  }
  if (i < 256) {
    wsf[i]       = b_xz[i] + b_hz[i];
    wsf[256 + i] = b_xr[i] + b_hr[i];
    wsf[512 + i] = b_xh[i] + b_hh[i];
  }
}

// fused[b] = [ mean_{22 rows} z , relu(u @ w_glob + b_glob) ]
__global__ void fused_head(const float* __restrict__ z, const float* __restrict__ u,
                           const float* __restrict__ w_glob, const float* __restrict__ b_glob,
                           float* __restrict__ out) {
  int b = blockIdx.x;
  int t = threadIdx.x;  // 128
  __shared__ float us[DGIN];
  if (t < DGIN) us[t] = u[b * DGIN + t];
  __syncthreads();
  const float* zb = z + (size_t)b * NPG * DBB;
  #pragma unroll
  for (int half = 0; half < 2; ++half) {
    int c = t + half * 128;
    float s = 0.f;
    #pragma unroll
    for (int r = 0; r < NPG; ++r) s += zb[r * DBB + c];
    out[(size_t)b * 384 + c] = s * (1.0f / NPG);
  }
  float acc = b_glob[t];
  #pragma unroll
  for (int k = 0; k < DGIN; ++k) acc += us[k] * w_glob[k * DGOUT + t];
  out[(size_t)b * 384 + 256 + t] = fmaxf(acc, 0.f);
}

#define MFMA16(a, b, c) __builtin_amdgcn_mfma_f32_16x16x32_bf16(a, b, c, 0, 0, 0)

// GRU body: 64 rows/block, 1024 thr (16 waves x 16 gate-cols, 48 f32 acc/lane).
// Weights: per-wave self-DMA'd 1KB identity spans, double-buffered, vmcnt-counted.
// Acts: z/ph staged per-32k-chunk (pad-40 LDS), xp persistent LDS (reused as T).
__global__ __launch_bounds__(1024)
void grnn_main(const float* __restrict__ z, const float* __restrict__ x,
               const float* __restrict__ prev_h, const float* __restrict__ b_proj,
               const __hip_bfloat16* __restrict__ wsb, const float* __restrict__ wsf,
               float* __restrict__ h_out) {
  __shared__ __align__(16) __hip_bfloat16 Wb[2][24576];   // 96 KB (Wb[1] holds x tile pre-loop)
  __shared__ __align__(16) __hip_bfloat16 ActC[2][64 * 40]; // 10 KB, pad-40
  __shared__ __align__(16) __hip_bfloat16 XP[64 * 256];   // 32 KB: xp, then T

  const int r0   = blockIdx.x * 64;
  const int tid  = threadIdx.x;
  const int wid  = tid >> 6;          // 0..15
  const int lane = tid & 63;
  const int l15  = lane & 15;
  const int lg   = lane >> 4;         // 0..3
  const int c0   = wid * 16;
  const int cgrp = (c0 >> 3) + (lg >> 1);
  const int lgl  = (lg & 1) * 4;

  const __hip_bfloat16* wpk = wsb + WTG_OFF;
  const __hip_bfloat16* hpk = wsb + WTHH_OFF;

  // ---- P0: stage x -> Wb[1] as [64][128] XOR-8 ----
  {
    int row = tid >> 4, c8 = tid & 15;
    const float* p = x + (size_t)(r0 + row) * DNODE + c8 * 8;
    f32x4 f0 = *(const f32x4*)p;
    f32x4 f1 = *(const f32x4*)(p + 4);
    bf16x8 o;
    o[0]=f2bf(f0[0]); o[1]=f2bf(f0[1]); o[2]=f2bf(f0[2]); o[3]=f2bf(f0[3]);
    o[4]=f2bf(f1[0]); o[5]=f2bf(f1[1]); o[6]=f2bf(f1[2]); o[7]=f2bf(f1[3]);
    *(bf16x8*)&Wb[1][row * 128 + (c8 ^ (row & 7)) * 8] = o;
  }
  __syncthreads();

  // ---- P1: DMA gate chunk0 -> Wb[0]; x_proj GEMM from Wb[1]; xp -> XP ----
  #pragma unroll
  for (int gs = 0; gs < 3; ++gs) {
    int ct = gs * 16 + wid;
    DMA16(wpk + ((size_t)(0 * 48 + ct) * 64 + lane) * 8, &Wb[0][ct * 512]);
  }
  f32x4 accp[4] = {};
  {
    const __hip_bfloat16* wp0 = wsb + (size_t)(c0 + l15) * DNODE + lg * 8;
    #pragma unroll
    for (int kb = 0; kb < 4; ++kb) {
      bf16x8 wp = *(const bf16x8*)(wp0 + kb * 32);
      const int gk = kb * 4 + lg;
      bf16x8 act[4];
      #pragma unroll
      for (int rt = 0; rt < 4; ++rt) {
        const int row = rt * 16 + l15;
        act[rt] = *(const bf16x8*)&Wb[1][row * 128 + (gk ^ (row & 7)) * 8];
      }
      __builtin_amdgcn_s_setprio(1);
      #pragma unroll
      for (int rt = 0; rt < 4; ++rt)
        accp[rt] = MFMA16(wp, act[rt], accp[rt]);
      __builtin_amdgcn_s_setprio(0);
    }
  }
  {
    float4 bp4 = *(const float4*)&b_proj[c0 + lg * 4];
    #pragma unroll
    for (int rt = 0; rt < 4; ++rt) {
      int r = rt * 16 + l15;
      bf16x4 o;
      o[0] = f2bf(fmaxf(accp[rt][0] + bp4.x, 0.f));
      o[1] = f2bf(fmaxf(accp[rt][1] + bp4.y, 0.f));
      o[2] = f2bf(fmaxf(accp[rt][2] + bp4.z, 0.f));
      o[3] = f2bf(fmaxf(accp[rt][3] + bp4.w, 0.f));
      *(bf16x4*)&XP[r * 256 + ((cgrp ^ (r & 7)) * 8) + lgl] = o;
    }
  }
  // stage z chunk0 -> ActC[0]
  {
    int row = tid >> 4, c2 = (tid & 15) * 2;
    const float* p = z + (size_t)(r0 + row) * DBB + c2;
    float a = p[0], b = p[1];
    unsigned int pk = (unsigned int)(unsigned short)f2bf(a) |
                      ((unsigned int)(unsigned short)f2bf(b) << 16);
    *(unsigned int*)&ActC[0][row * 40 + (c2 >> 3) * 8 + (c2 & 7)] = pk;
  }
  __syncthreads();   // full barrier once (x dead, z0+xp visible; Wb[0] handled by vmcnt)

  // ---- P2: gate sweep, 24 BK=32 chunks ----
  f32x4 accz[4] = {}, accr[4] = {}, acch[4] = {};
  #pragma unroll
  for (int kc = 0; kc < 24; ++kc) {
    const int kn = kc + 1;
    // stage next act chunk first (so compiler's f32-load waits don't drain our DMAs)
    if (kn < 8 || (kn >= 16 && kn < 24)) {
      const float* src = (kn < 8) ? z : prev_h;
      const int kofs = (kn < 8 ? kn : kn - 16) * 32;
      int row = tid >> 4, c2 = (tid & 15) * 2;
      const float* p = src + (size_t)(r0 + row) * DBB + kofs + c2;
      float a = p[0], b = p[1];
      unsigned int pk = (unsigned int)(unsigned short)f2bf(a) |
                        ((unsigned int)(unsigned short)f2bf(b) << 16);
      *(unsigned int*)&ActC[kn & 1][row * 40 + (c2 >> 3) * 8 + (c2 & 7)] = pk;
    }
    __builtin_amdgcn_sched_barrier(0);
    // DMA next weight chunk (3 spans if kn<16 (z,r,h), else 2 (z,r))
    if (kn < 24) {
      const int ns = (kn < 16) ? 3 : 2;
      #pragma unroll
      for (int gs = 0; gs < 3; ++gs) {
        if (gs < ns) {
          int ct = gs * 16 + wid;
          DMA16(wpk + ((size_t)(kn * 48 + ct) * 64 + lane) * 8, &Wb[kn & 1][ct * 512]);
        }
      }
    }
    __builtin_amdgcn_sched_barrier(0);
    // barrier only when this chunk reads a staged ActC buffer
    if (kc < 8 || kc >= 16) LBAR();
    // wait for THIS chunk's weights (ours): allow the just-issued DMAs to stay in flight
    if (kc < 15)      VMWAIT(3);
    else if (kc < 23) VMWAIT(2);
    else              VMWAIT(0);
    // fragments
    bf16x8 act[4];
    #pragma unroll
    for (int rt = 0; rt < 4; ++rt) {
      const int row = rt * 16 + l15;
      if (kc < 8 || kc >= 16)
        act[rt] = *(const bf16x8*)&ActC[kc & 1][row * 40 + lg * 8];
      else {
        const int gk = (kc - 8) * 4 + lg;
        act[rt] = *(const bf16x8*)&XP[row * 256 + (gk ^ (row & 7)) * 8];
      }
    }
    bf16x8 wz = *(const bf16x8*)&Wb[kc & 1][(0 * 16 + wid) * 512 + lane * 8];
    bf16x8 wr = *(const bf16x8*)&Wb[kc & 1][(1 * 16 + wid) * 512 + lane * 8];
    bf16x8 wh;
    if (kc < 16) wh = *(const bf16x8*)&Wb[kc & 1][(2 * 16 + wid) * 512 + lane * 8];
    __builtin_amdgcn_s_setprio(1);
    #pragma unroll
    for (int rt = 0; rt < 4; ++rt) {
      accz[rt] = MFMA16(wz, act[rt], accz[rt]);
      accr[rt] = MFMA16(wr, act[rt], accr[rt]);
      if (kc < 16) acch[rt] = MFMA16(wh, act[rt], acch[rt]);
    }
    __builtin_amdgcn_s_setprio(0);
    // protect ActC[kc&1] from the stage at iter kc+1 (writes same parity at kc+2)
    if (kc < 7 || (kc >= 16 && kc < 23)) LBAR();
  }

  // ---- P3: T = ph * sigmoid(A_r + br) -> XP (xp dead); DMA Whh chunk0 ----
  DMA16(hpk + ((size_t)(0 * 16 + wid) * 64 + lane) * 8, &Wb[0][wid * 512]);
  f32x4 phv[4];
  {
    float4 br4 = *(const float4*)&wsf[256 + c0 + lg * 4];
    #pragma unroll
    for (int rt = 0; rt < 4; ++rt) {
      int r = rt * 16 + l15;
      phv[rt] = *(const f32x4*)&prev_h[(size_t)(r0 + r) * DBB + c0 + lg * 4];
      bf16x4 o;
      o[0] = f2bf(phv[rt][0] * fsig(accr[rt][0] + br4.x));
      o[1] = f2bf(phv[rt][1] * fsig(accr[rt][1] + br4.y));
      o[2] = f2bf(phv[rt][2] * fsig(accr[rt][2] + br4.z));
      o[3] = f2bf(phv[rt][3] * fsig(accr[rt][3] + br4.w));
      *(bf16x4*)&XP[r * 256 + ((cgrp ^ (r & 7)) * 8) + lgl] = o;
    }
  }
  LBAR();  // T visible to all waves

  // ---- P4: acch += T @ W_hh : 8 chunks, self-DMA'd, barrier-free ----
  #pragma unroll
  for (int s = 0; s < 8; ++s) {
    if (s < 7)
      DMA16(hpk + ((size_t)((s + 1) * 16 + wid) * 64 + lane) * 8, &Wb[(s + 1) & 1][wid * 512]);
    __builtin_amdgcn_sched_barrier(0);
    if (s < 7) VMWAIT(1); else VMWAIT(0);
    bf16x8 act[4];
    #pragma unroll
    for (int rt = 0; rt < 4; ++rt) {
      const int row = rt * 16 + l15;
      const int gk = s * 4 + lg;
      act[rt] = *(const bf16x8*)&XP[row * 256 + (gk ^ (row & 7)) * 8];
    }
    bf16x8 wv = *(const bf16x8*)&Wb[s & 1][wid * 512 + lane * 8];
    __builtin_amdgcn_s_setprio(1);
    #pragma unroll
    for (int rt = 0; rt < 4; ++rt)
      acch[rt] = MFMA16(wv, act[rt], acch[rt]);
    __builtin_amdgcn_s_setprio(0);
  }

  // ---- epilogue: h = Z*ph + (1-Z)*tanh(A_h) ----
  {
    float4 bz4 = *(const float4*)&wsf[c0 + lg * 4];
    float4 bh4 = *(const float4*)&wsf[512 + c0 + lg * 4];
    #pragma unroll
    for (int rt = 0; rt < 4; ++rt) {
      int r = rt * 16 + l15;
      f32x4 hv;
      float zg = fsig(accz[rt][0] + bz4.x);
      hv[0] = zg * phv[rt][0] + (1.f - zg) * ftanh(acch[rt][0] + bh4.x);
      zg = fsig(accz[rt][1] + bz4.y);
      hv[1] = zg * phv[rt][1] + (1.f - zg) * ftanh(acch[rt][1] + bh4.y);
      zg = fsig(accz[rt][2] + bz4.z);
      hv[2] = zg * phv[rt][2] + (1.f - zg) * ftanh(acch[rt][2] + bh4.z);
      zg = fsig(accz[rt][3] + bz4.w);
      hv[3] = zg * phv[rt][3] + (1.f - zg) * ftanh(acch[rt][3] + bh4.w);
      *(f32x4*)&h_out[(size_t)(r0 + r) * DBB + c0 + lg * 4] = hv;
    }
  }
}

extern "C" void kernel_launch(void* const* d_in, const int* in_sizes, int n_in,
                              void* d_out, int out_size, void* d_ws, size_t ws_size,
                              hipStream_t stream) {
  const float* z      = (const float*)d_in[0];
  const float* u      = (const float*)d_in[1];
  const float* x      = (const float*)d_in[2];
  const float* prev_h = (const float*)d_in[6];
  const float* w_proj = (const float*)d_in[7];
  const float* b_proj = (const float*)d_in[8];
  const float* w_glob = (const float*)d_in[9];
  const float* b_glob = (const float*)d_in[10];
  const float* W_xz   = (const float*)d_in[11];
  const float* b_xz   = (const float*)d_in[12];
  const float* W_hz   = (const float*)d_in[13];
  const float* b_hz   = (const float*)d_in[14];
  const float* W_xr   = (const float*)d_in[15];
  const float* b_xr   = (const float*)d_in[16];
  const float* W_hr   = (const float*)d_in[17];
  const float* b_hr   = (const float*)d_in[18];
  const float* W_xh   = (const float*)d_in[19];
  const float* b_xh   = (const float*)d_in[20];
  const float* W_hh   = (const float*)d_in[21];
  const float* b_hh   = (const float*)d_in[22];

  __hip_bfloat16* wsb = (__hip_bfloat16*)d_ws;
  float* wsf = (float*)((char*)d_ws + (size_t)WS_BF16_ELEMS * 2);

  float* fused = (float*)d_out;
  float* h_out = fused + (size_t)BGRAPH * 384;

  pack_weights<<<dim3(WS_BF16_ELEMS / 256), dim3(256), 0, stream>>>(
      w_proj, W_xz, W_hz, W_xr, W_hr, W_xh, W_hh,
      b_xz, b_hz, b_xr, b_hr, b_xh, b_hh, wsb, wsf);

  fused_head<<<dim3(BGRAPH), dim3(128), 0, stream>>>(z, u, w_glob, b_glob, fused);

  grnn_main<<<dim3(NNODES / 64), dim3(1024), 0, stream>>>(
      z, x, prev_h, b_proj, wsb, wsf, h_out);
}

// Round 11
// 211.438 us; speedup vs baseline: 2.1918x; 1.1103x over previous
//
#include <hip/hip_runtime.h>
#include <hip/hip_bf16.h>

#define NNODES 90112
#define BGRAPH 4096
#define NPG 22
#define DBB 256
#define DNODE 128
#define DPROJ 256
#define DGIN 64
#define DGOUT 128

// ws bf16 layout (identical to round 10):
//   [0, 32768)           WTp  [256 cols][128 k]  (w_proj^T, read per-wave)
//   [32768, 622592)      Wpk  gate weights, DMA-packed:
//                        elem ((kc*48 + ct)*64 + lane)*8 + e ; kc 0..23,
//                        ct 0..47 (ct>>4 = gate z/r/h, col = (ct&15)*16 + (lane&15)),
//                        k = kc*32 + (lane>>4)*8 + e.  (h spans for kc>=16 zero, never DMA'd)
//   [622592, 688128)     Whhpk: kc 0..7, ct 0..15, col = ct*16+l15.
// f32 tail: bz[256], br[256], bh[256]
#define WTG_OFF   32768
#define WTHH_OFF  622592
#define WS_BF16_ELEMS 688128

typedef __attribute__((ext_vector_type(8))) short bf16x8;
typedef __attribute__((ext_vector_type(4))) short bf16x4;
typedef __attribute__((ext_vector_type(4))) float f32x4;
typedef __attribute__((ext_vector_type(2))) float f32x2;

__device__ __forceinline__ short f2bf(float f) {
  __hip_bfloat16 h = __float2bfloat16(f);
  return *reinterpret_cast<short*>(&h);
}
__device__ __forceinline__ float bf2f(short s) {
  union { unsigned int u; float f; } c;
  c.u = ((unsigned int)(unsigned short)s) << 16;
  return c.f;
}
__device__ __forceinline__ float fsig(float xv) {
  return __fdividef(1.0f, 1.0f + __expf(-xv));
}
__device__ __forceinline__ float ftanh(float xv) {
  return 1.0f - __fdividef(2.0f, __expf(2.0f * xv) + 1.0f);
}

#define DMA16(gsrc, ldst)                                                        \
  __builtin_amdgcn_global_load_lds(                                              \
      (const __attribute__((address_space(1))) void*)(gsrc),                     \
      (__attribute__((address_space(3))) void*)(ldst), 16, 0, 0)

template<int N>
__device__ __forceinline__ void vmwaitN() {
  static_assert(N >= 0 && N <= 6, "vmcnt range");
  if constexpr (N == 0) asm volatile("s_waitcnt vmcnt(0)" ::: "memory");
  else if constexpr (N == 1) asm volatile("s_waitcnt vmcnt(1)" ::: "memory");
  else if constexpr (N == 2) asm volatile("s_waitcnt vmcnt(2)" ::: "memory");
  else if constexpr (N == 3) asm volatile("s_waitcnt vmcnt(3)" ::: "memory");
  else if constexpr (N == 4) asm volatile("s_waitcnt vmcnt(4)" ::: "memory");
  else if constexpr (N == 5) asm volatile("s_waitcnt vmcnt(5)" ::: "memory");
  else asm volatile("s_waitcnt vmcnt(6)" ::: "memory");
  __builtin_amdgcn_sched_barrier(0);
}
#define LBAR() do { asm volatile("s_waitcnt lgkmcnt(0)" ::: "memory");           \
                    __builtin_amdgcn_s_barrier(); } while (0)

__global__ void pack_weights(const float* __restrict__ w_proj,
                             const float* __restrict__ W_xz, const float* __restrict__ W_hz,
                             const float* __restrict__ W_xr, const float* __restrict__ W_hr,
                             const float* __restrict__ W_xh, const float* __restrict__ W_hh,
                             const float* __restrict__ b_xz, const float* __restrict__ b_hz,
                             const float* __restrict__ b_xr, const float* __restrict__ b_hr,
                             const float* __restrict__ b_xh, const float* __restrict__ b_hh,
                             __hip_bfloat16* __restrict__ wsb, float* __restrict__ wsf) {
  int i = blockIdx.x * 256 + threadIdx.x;
  if (i < 32768) {
    int c = i >> 7, k = i & 127;
    wsb[i] = __float2bfloat16(w_proj[k * DPROJ + c]);
  } else if (i < WTHH_OFF) {
    int j = i - WTG_OFF;
    int kc  = j / 24576;
    int rem = j - kc * 24576;
    int ct  = rem >> 9;
    int q   = rem & 511;
    int l   = q >> 3, e = q & 7;
    int l15 = l & 15, kg = l >> 4;
    int k   = kc * 32 + kg * 8 + e;
    int g   = ct >> 4;
    int c   = (ct & 15) * 16 + l15;
    float v;
    if (g == 0)      v = (k < 512) ? W_xz[k * 256 + c] : W_hz[(k - 512) * 256 + c];
    else if (g == 1) v = (k < 512) ? W_xr[k * 256 + c] : W_hr[(k - 512) * 256 + c];
    else             v = (k < 512) ? W_xh[k * 256 + c] : 0.0f;
    wsb[i] = __float2bfloat16(v);
  } else if (i < WS_BF16_ELEMS) {
    int j = i - WTHH_OFF;
    int kc  = j >> 13;
    int rem = j & 8191;
    int ct  = rem >> 9;
    int q   = rem & 511;
    int l   = q >> 3, e = q & 7;
    int l15 = l & 15, kg = l >> 4;
    int k   = kc * 32 + kg * 8 + e;
    int c   = ct * 16 + l15;
    wsb[i] = __float2bfloat16(W_hh[k * 256 + c]);
  }
  if (i < 256) {
    wsf[i]       = b_xz[i] + b_hz[i];
    wsf[256 + i] = b_xr[i] + b_hr[i];
    wsf[512 + i] = b_xh[i] + b_hh[i];
  }
}

__global__ void fused_head(const float* __restrict__ z, const float* __restrict__ u,
                           const float* __restrict__ w_glob, const float* __restrict__ b_glob,
                           float* __restrict__ out) {
  int b = blockIdx.x;
  int t = threadIdx.x;  // 128
  __shared__ float us[DGIN];
  if (t < DGIN) us[t] = u[b * DGIN + t];
  __syncthreads();
  const float* zb = z + (size_t)b * NPG * DBB;
  #pragma unroll
  for (int half = 0; half < 2; ++half) {
    int c = t + half * 128;
    float s = 0.f;
    #pragma unroll
    for (int r = 0; r < NPG; ++r) s += zb[r * DBB + c];
    out[(size_t)b * 384 + c] = s * (1.0f / NPG);
  }
  float acc = b_glob[t];
  #pragma unroll
  for (int k = 0; k < DGIN; ++k) acc += us[k] * w_glob[k * DGOUT + t];
  out[(size_t)b * 384 + 256 + t] = fmaxf(acc, 0.f);
}

#define MFMA16(a, b, c) __builtin_amdgcn_mfma_f32_16x16x32_bf16(a, b, c, 0, 0, 0)

// One gate-sweep step (kc = KC). Per-gate counted vmcnt with 6-span FIFO.
template<int KC>
__device__ __forceinline__ void gstep(
    const float* __restrict__ z, const float* __restrict__ prev_h,
    const __hip_bfloat16* __restrict__ wpk,
    __hip_bfloat16* Wb, __hip_bfloat16* ActC, __hip_bfloat16* XP,
    int tid, int r0, int l15, int lg, int wid, int lane,
    f32x4 (&accz)[4], f32x4 (&accr)[4], f32x4 (&acch)[4]) {
  constexpr int  KN       = KC + 1;
  constexpr bool do_stage = (KN >= 1 && KN <= 7) || (KN >= 16 && KN <= 23);
  constexpr bool bar      = (KC >= 1 && KC <= 7) || (KC >= 15 && KC <= 23);
  constexpr bool staged   = (KC < 8) || (KC >= 16);
  constexpr bool has_h    = (KC < 16);
  constexpr int NZ = (KC <= 14) ? 5 : (KC == 15) ? 4 : (KC <= 22) ? 3 : 1;
  constexpr int NR = (KC <= 14) ? 5 : (KC == 15) ? 4 : (KC <= 21) ? 3 : (KC == 22) ? 2 : 0;
  constexpr int NH = (KC <= 14) ? 5 : 4;

  // stage-load for next staged chunk: issue at top, pack at bottom
  f32x2 sl;
  int srow = tid >> 4, sc2 = (tid & 15) * 2;
  if constexpr (do_stage) {
    const float* src = (KN < 8) ? z : prev_h;
    constexpr int kofs = (KN < 8 ? KN : KN - 16) * 32;
    sl = *(const f32x2*)(src + (size_t)(r0 + srow) * DBB + kofs + sc2);
  }
  if constexpr (bar) LBAR();

  bf16x8 act[4];
  #pragma unroll
  for (int rt = 0; rt < 4; ++rt) {
    const int row = rt * 16 + l15;
    if constexpr (staged)
      act[rt] = *(const bf16x8*)&ActC[(KC % 3) * (64 * 40) + row * 40 + lg * 8];
    else {
      const int gk = (KC - 8) * 4 + lg;
      act[rt] = *(const bf16x8*)&XP[row * 256 + ((gk ^ (row & 7)) * 8)];
    }
  }

  // ---- z gate ----
  vmwaitN<NZ>();
  {
    bf16x8 w = *(const bf16x8*)&Wb[((KC & 1) * 3 + 0) * 8192 + wid * 512 + lane * 8];
    __builtin_amdgcn_s_setprio(1);
    #pragma unroll
    for (int rt = 0; rt < 4; ++rt) accz[rt] = MFMA16(w, act[rt], accz[rt]);
    __builtin_amdgcn_s_setprio(0);
  }
  if constexpr (KC + 2 <= 23)
    DMA16(wpk + (((size_t)(KC + 2) * 48 + 0 * 16 + wid) * 64 + lane) * 8,
          Wb + (((KC + 2) & 1) * 3 + 0) * 8192 + wid * 512);

  // ---- r gate ----
  vmwaitN<NR>();
  {
    bf16x8 w = *(const bf16x8*)&Wb[((KC & 1) * 3 + 1) * 8192 + wid * 512 + lane * 8];
    __builtin_amdgcn_s_setprio(1);
    #pragma unroll
    for (int rt = 0; rt < 4; ++rt) accr[rt] = MFMA16(w, act[rt], accr[rt]);
    __builtin_amdgcn_s_setprio(0);
  }
  if constexpr (KC + 2 <= 23)
    DMA16(wpk + (((size_t)(KC + 2) * 48 + 1 * 16 + wid) * 64 + lane) * 8,
          Wb + (((KC + 2) & 1) * 3 + 1) * 8192 + wid * 512);

  // ---- h gate (k<512 only) ----
  if constexpr (has_h) {
    vmwaitN<NH>();
    bf16x8 w = *(const bf16x8*)&Wb[((KC & 1) * 3 + 2) * 8192 + wid * 512 + lane * 8];
    __builtin_amdgcn_s_setprio(1);
    #pragma unroll
    for (int rt = 0; rt < 4; ++rt) acch[rt] = MFMA16(w, act[rt], acch[rt]);
    __builtin_amdgcn_s_setprio(0);
    if constexpr (KC + 2 <= 15)
      DMA16(wpk + (((size_t)(KC + 2) * 48 + 2 * 16 + wid) * 64 + lane) * 8,
            Wb + (((KC + 2) & 1) * 3 + 2) * 8192 + wid * 512);
  }

  if constexpr (do_stage) {
    unsigned int pk = (unsigned int)(unsigned short)f2bf(sl[0]) |
                      ((unsigned int)(unsigned short)f2bf(sl[1]) << 16);
    *(unsigned int*)&ActC[(KN % 3) * (64 * 40) + srow * 40 + sc2] = pk;
  }
}

// One Whh step (ring-4 slots, depth-3 DMA).
template<int S>
__device__ __forceinline__ void hstep(
    const __hip_bfloat16* __restrict__ hpk, __hip_bfloat16* Wb, __hip_bfloat16* XP,
    int l15, int lg, int wid, int lane, f32x4 (&acch)[4]) {
  constexpr int NW = (S <= 5) ? 2 : (S == 6) ? 1 : 0;
  bf16x8 act[4];
  #pragma unroll
  for (int rt = 0; rt < 4; ++rt) {
    const int row = rt * 16 + l15;
    const int gk = S * 4 + lg;
    act[rt] = *(const bf16x8*)&XP[row * 256 + ((gk ^ (row & 7)) * 8)];
  }
  vmwaitN<NW>();
  bf16x8 w = *(const bf16x8*)&Wb[(S % 4) * 8192 + wid * 512 + lane * 8];
  __builtin_amdgcn_s_setprio(1);
  #pragma unroll
  for (int rt = 0; rt < 4; ++rt) acch[rt] = MFMA16(w, act[rt], acch[rt]);
  __builtin_amdgcn_s_setprio(0);
  if constexpr (S + 3 <= 7)
    DMA16(hpk + (((size_t)(S + 3) * 16 + wid) * 64 + lane) * 8,
          Wb + ((S + 3) % 4) * 8192 + wid * 512);
}

// GRU body: 64 rows/block, 1024 thr (16 waves x 16 gate-cols, 48 f32 acc/lane).
__global__ __launch_bounds__(1024)
void grnn_main(const float* __restrict__ z, const float* __restrict__ x,
               const float* __restrict__ prev_h, const float* __restrict__ b_proj,
               const __hip_bfloat16* __restrict__ wsb, const float* __restrict__ wsf,
               float* __restrict__ h_out) {
  __shared__ __align__(16) __hip_bfloat16 Wb[6 * 8192];       // 96 KB weight slots
  __shared__ __align__(16) __hip_bfloat16 Xs[64 * 128];       // 16 KB x tile
  __shared__ __align__(16) __hip_bfloat16 XP[64 * 256];       // 32 KB xp -> T
  __shared__ __align__(16) __hip_bfloat16 ActC[3 * 64 * 40];  // 15 KB act ring

  const int r0   = blockIdx.x * 64;
  const int tid  = threadIdx.x;
  const int wid  = tid >> 6;
  const int lane = tid & 63;
  const int l15  = lane & 15;
  const int lg   = lane >> 4;
  const int c0   = wid * 16;
  const int cgrp = (c0 >> 3) + (lg >> 1);
  const int lgl  = (lg & 1) * 4;

  const __hip_bfloat16* wpk = wsb + WTG_OFF;
  const __hip_bfloat16* hpk = wsb + WTHH_OFF;

  // ---- P0: stage x -> Xs ----
  {
    int row = tid >> 4, c8 = tid & 15;
    const float* p = x + (size_t)(r0 + row) * DNODE + c8 * 8;
    f32x4 f0 = *(const f32x4*)p;
    f32x4 f1 = *(const f32x4*)(p + 4);
    bf16x8 o;
    o[0]=f2bf(f0[0]); o[1]=f2bf(f0[1]); o[2]=f2bf(f0[2]); o[3]=f2bf(f0[3]);
    o[4]=f2bf(f1[0]); o[5]=f2bf(f1[1]); o[6]=f2bf(f1[2]); o[7]=f2bf(f1[3]);
    *(bf16x8*)&Xs[row * 128 + (c8 ^ (row & 7)) * 8] = o;
  }
  __syncthreads();

  // ---- P1: z chunk0 load; x_proj GEMM; 6-deep DMA prologue; packs; LBAR ----
  f32x2 sl0;
  {
    int row = tid >> 4, c2 = (tid & 15) * 2;
    sl0 = *(const f32x2*)(z + (size_t)(r0 + row) * DBB + c2);
  }
  f32x4 accp[4] = {};
  {
    const __hip_bfloat16* wp0 = wsb + (size_t)(c0 + l15) * DNODE + lg * 8;
    #pragma unroll
    for (int kb = 0; kb < 4; ++kb) {
      bf16x8 wp = *(const bf16x8*)(wp0 + kb * 32);
      const int gk = kb * 4 + lg;
      bf16x8 act[4];
      #pragma unroll
      for (int rt = 0; rt < 4; ++rt) {
        const int row = rt * 16 + l15;
        act[rt] = *(const bf16x8*)&Xs[row * 128 + (gk ^ (row & 7)) * 8];
      }
      __builtin_amdgcn_s_setprio(1);
      #pragma unroll
      for (int rt = 0; rt < 4; ++rt)
        accp[rt] = MFMA16(wp, act[rt], accp[rt]);
      __builtin_amdgcn_s_setprio(0);
    }
  }
  // prologue DMAs: chunks 0,1 x gates z,r,h (FIFO order z,r,h per chunk)
  #pragma unroll
  for (int c = 0; c < 2; ++c)
    #pragma unroll
    for (int g = 0; g < 3; ++g)
      DMA16(wpk + (((size_t)c * 48 + g * 16 + wid) * 64 + lane) * 8,
            Wb + ((c & 1) * 3 + g) * 8192 + wid * 512);
  // packs
  {
    int row = tid >> 4, c2 = (tid & 15) * 2;
    unsigned int pk = (unsigned int)(unsigned short)f2bf(sl0[0]) |
                      ((unsigned int)(unsigned short)f2bf(sl0[1]) << 16);
    *(unsigned int*)&ActC[0 * (64 * 40) + row * 40 + c2] = pk;
  }
  {
    float4 bp4 = *(const float4*)&b_proj[c0 + lg * 4];
    #pragma unroll
    for (int rt = 0; rt < 4; ++rt) {
      int r = rt * 16 + l15;
      bf16x4 o;
      o[0] = f2bf(fmaxf(accp[rt][0] + bp4.x, 0.f));
      o[1] = f2bf(fmaxf(accp[rt][1] + bp4.y, 0.f));
      o[2] = f2bf(fmaxf(accp[rt][2] + bp4.z, 0.f));
      o[3] = f2bf(fmaxf(accp[rt][3] + bp4.w, 0.f));
      *(bf16x4*)&XP[r * 256 + ((cgrp ^ (r & 7)) * 8) + lgl] = o;
    }
  }
  LBAR();

  // ---- P2: 24-step gate sweep ----
  f32x4 accz[4] = {}, accr[4] = {}, acch[4] = {};
  #define GS(K) gstep<K>(z, prev_h, wpk, Wb, ActC, XP, tid, r0, l15, lg, wid, lane, accz, accr, acch)
  GS(0);  GS(1);  GS(2);  GS(3);  GS(4);  GS(5);  GS(6);  GS(7);
  GS(8);  GS(9);  GS(10); GS(11); GS(12); GS(13); GS(14); GS(15);
  GS(16); GS(17); GS(18); GS(19); GS(20); GS(21); GS(22); GS(23);
  #undef GS

  // ---- P3: Whh DMA prologue; phv; T = ph*sigmoid(A_r+br) -> XP; LBAR ----
  #pragma unroll
  for (int s = 0; s < 3; ++s)
    DMA16(hpk + (((size_t)s * 16 + wid) * 64 + lane) * 8, Wb + (s % 4) * 8192 + wid * 512);
  f32x4 phv[4];
  {
    float4 br4 = *(const float4*)&wsf[256 + c0 + lg * 4];
    #pragma unroll
    for (int rt = 0; rt < 4; ++rt) {
      int r = rt * 16 + l15;
      phv[rt] = *(const f32x4*)&prev_h[(size_t)(r0 + r) * DBB + c0 + lg * 4];
      bf16x4 o;
      o[0] = f2bf(phv[rt][0] * fsig(accr[rt][0] + br4.x));
      o[1] = f2bf(phv[rt][1] * fsig(accr[rt][1] + br4.y));
      o[2] = f2bf(phv[rt][2] * fsig(accr[rt][2] + br4.z));
      o[3] = f2bf(phv[rt][3] * fsig(accr[rt][3] + br4.w));
      *(bf16x4*)&XP[r * 256 + ((cgrp ^ (r & 7)) * 8) + lgl] = o;
    }
  }
  LBAR();

  // ---- P4: acch += T @ W_hh ----
  #define HS(S) hstep<S>(hpk, Wb, XP, l15, lg, wid, lane, acch)
  HS(0); HS(1); HS(2); HS(3); HS(4); HS(5); HS(6); HS(7);
  #undef HS

  // ---- epilogue ----
  {
    float4 bz4 = *(const float4*)&wsf[c0 + lg * 4];
    float4 bh4 = *(const float4*)&wsf[512 + c0 + lg * 4];
    #pragma unroll
    for (int rt = 0; rt < 4; ++rt) {
      int r = rt * 16 + l15;
      f32x4 hv;
      float zg = fsig(accz[rt][0] + bz4.x);
      hv[0] = zg * phv[rt][0] + (1.f - zg) * ftanh(acch[rt][0] + bh4.x);
      zg = fsig(accz[rt][1] + bz4.y);
      hv[1] = zg * phv[rt][1] + (1.f - zg) * ftanh(acch[rt][1] + bh4.y);
      zg = fsig(accz[rt][2] + bz4.z);
      hv[2] = zg * phv[rt][2] + (1.f - zg) * ftanh(acch[rt][2] + bh4.z);
      zg = fsig(accz[rt][3] + bz4.w);
      hv[3] = zg * phv[rt][3] + (1.f - zg) * ftanh(acch[rt][3] + bh4.w);
      *(f32x4*)&h_out[(size_t)(r0 + r) * DBB + c0 + lg * 4] = hv;
    }
  }
}

extern "C" void kernel_launch(void* const* d_in, const int* in_sizes, int n_in,
                              void* d_out, int out_size, void* d_ws, size_t ws_size,
                              hipStream_t stream) {
  const float* z      = (const float*)d_in[0];
  const float* u      = (const float*)d_in[1];
  const float* x      = (const float*)d_in[2];
  const float* prev_h = (const float*)d_in[6];
  const float* w_proj = (const float*)d_in[7];
  const float* b_proj = (const float*)d_in[8];
  const float* w_glob = (const float*)d_in[9];
  const float* b_glob = (const float*)d_in[10];
  const float* W_xz   = (const float*)d_in[11];
  const float* b_xz   = (const float*)d_in[12];
  const float* W_hz   = (const float*)d_in[13];
  const float* b_hz   = (const float*)d_in[14];
  const float* W_xr   = (const float*)d_in[15];
  const float* b_xr   = (const float*)d_in[16];
  const float* W_hr   = (const float*)d_in[17];
  const float* b_hr   = (const float*)d_in[18];
  const float* W_xh   = (const float*)d_in[19];
  const float* b_xh   = (const float*)d_in[20];
  const float* W_hh   = (const float*)d_in[21];
  const float* b_hh   = (const float*)d_in[22];

  __hip_bfloat16* wsb = (__hip_bfloat16*)d_ws;
  float* wsf = (float*)((char*)d_ws + (size_t)WS_BF16_ELEMS * 2);

  float* fused = (float*)d_out;
  float* h_out = fused + (size_t)BGRAPH * 384;

  pack_weights<<<dim3(WS_BF16_ELEMS / 256), dim3(256), 0, stream>>>(
      w_proj, W_xz, W_hz, W_xr, W_hr, W_xh, W_hh,
      b_xz, b_hz, b_xr, b_hr, b_xh, b_hh, wsb, wsf);

  fused_head<<<dim3(BGRAPH), dim3(128), 0, stream>>>(z, u, w_glob, b_glob, fused);

  grnn_main<<<dim3(NNODES / 64), dim3(1024), 0, stream>>>(
      z, x, prev_h, b_proj, wsb, wsf, h_out);
}